// Round 3
// baseline (225.761 us; speedup 1.0000x reference)
//
#include <hip/hip_runtime.h>
#include <math.h>

#define N      512
#define RNUM   4
#define BNUM   2
#define NSLICE (RNUM * BNUM)
#define TILE   128               // (a,b) tile is 128x128, 256 threads x (8x8)
#define CT     32                // c-chunk per LDS stage
#define PAD    4
#define STRIDE (TILE + PAD)      // 132 floats
#define CSPLIT 4                 // c-split -> 512 main blocks
#define NCOLB  16                // colsum-role blocks (8 slices x 2 col-halves)
#define SCALE  0.0625f           // 1/16 = (1/2 from relu split) * (1/8 weight)

__device__ __forceinline__ float sigmoidf_(float x) {
  return 1.0f / (1.0f + __expf(-x));
}

__global__ void zero_out_kernel(float* out) { out[0] = 0.0f; }

// One thread per (b,i,j): float4 over r, writes 4 slice planes with sigmoid+mask.
// Block 0 thread 0 also zeroes the output accumulator.
__global__ __launch_bounds__(256) void prep_kernel(const float* __restrict__ logits,
                                                   const int* __restrict__ masks,
                                                   float* __restrict__ P,
                                                   float* __restrict__ out) {
  if (blockIdx.x == 0 && threadIdx.x == 0) out[0] = 0.0f;
  int t = blockIdx.x * 256 + threadIdx.x;      // 0 .. B*N*N-1
  int b = t / (N * N);
  int rem = t - b * (N * N);
  int i = rem / N;
  int j = rem - i * N;
  float4 lg = *(const float4*)(logits + (size_t)t * 4);
  float mm = ((masks[b * N + i] > 0) && (masks[b * N + j] > 0)) ? 1.0f : 0.0f;
  size_t base = (size_t)b * RNUM * N * N + rem;
  P[base + 0 * (size_t)N * N] = mm * sigmoidf_(lg.x);
  P[base + 1 * (size_t)N * N] = mm * sigmoidf_(lg.y);
  P[base + 2 * (size_t)N * N] = mm * sigmoidf_(lg.z);
  P[base + 3 * (size_t)N * N] = mm * sigmoidf_(lg.w);
}

// Work kernel, two roles by blockIdx.x:
//  bid <  NCOLB : colsum role — per-column v = csum*(N - csum); adds
//                 SCALE * sum(v) to out  (the factorized Sum(x) part)
//  bid >= NCOLB : main role — adds SCALE * Sum|x| over its
//                 (slice, 128x128 (a,b) tile, c-range) via LDS-staged tiles.
// LDS layout transposed + XOR swizzle: element (c, i) at row c, col
// pcol = (((i>>2) ^ c4) & 31)*4 + (i&3), c4 = (c&31)>>2.  Writes 2-way (free),
// A-reads 2-way b128, B-reads broadcast — verified bank math, stride 132.
template <bool USE_P>
__global__ __launch_bounds__(256, 3) void work_kernel(const float* __restrict__ P,
                                                      const float* __restrict__ logits,
                                                      const int* __restrict__ masks,
                                                      float* __restrict__ out) {
  __shared__ __align__(16) float tA[CT][STRIDE];
  __shared__ __align__(16) float tB[CT][STRIDE];
  __shared__ float wsum[4];

  const int tid = threadIdx.x;
  const int bid = blockIdx.x;

  if (bid < NCOLB) {
    // ---- colsum role: Sum_c csum_c * (N - csum_c) per slice ----
    const int s    = bid >> 1;
    const int half = bid & 1;
    const int c    = half * 256 + tid;
    const int bb   = s >> 2;
    const int r    = s & 3;
    float sum = 0.0f;
    if (USE_P) {
      const float* Ps = P + (size_t)s * N * N + c;
#pragma unroll 8
      for (int a = 0; a < N; ++a) sum += Ps[(size_t)a * N];
    } else {
      const int* mrow = masks + bb * N;
      float mc = (mrow[c] > 0) ? 1.0f : 0.0f;
#pragma unroll 4
      for (int a = 0; a < N; ++a) {
        float ma = (mrow[a] > 0) ? 1.0f : 0.0f;
        size_t idx = ((size_t)(bb * N + a) * N + c) * RNUM + r;
        sum += sigmoidf_(logits[idx]) * ma * mc;
      }
    }
    float v = sum * ((float)N - sum);
    for (int off = 32; off > 0; off >>= 1) v += __shfl_down(v, off, 64);
    const int wid = tid >> 6;
    if ((tid & 63) == 0) wsum[wid] = v;
    __syncthreads();
    if (tid == 0)
      atomicAdd(out, (wsum[0] + wsum[1] + wsum[2] + wsum[3]) * SCALE);
    return;
  }

  // ---- main role: Sum |rab - a_c*b_c| ----
  const int m  = bid - NCOLB;
  const int bt = m & 3;
  const int at = (m >> 2) & 3;
  const int s  = (m >> 4) & 7;
  const int cz = m >> 7;                    // 0..CSPLIT-1
  const int a0 = at * TILE;
  const int b0 = bt * TILE;
  const int bb = s >> 2;
  const int r  = s & 3;
  const int cbeg = cz * (N / CSPLIT);
  const int cend = cbeg + (N / CSPLIT);

  const int ta = tid & 15;    // a rows: a0 + ta*4 + x  and  a0 + 64 + ta*4 + x
  const int tb = tid >> 4;    // b cols: b0 + tb*4 + y  and  b0 + 64 + tb*4 + y

  const float* Ps = P + (size_t)s * N * N;
  const int* mrow = masks + bb * N;

  float rab[8][8];
  if (USE_P) {
#pragma unroll
    for (int x = 0; x < 8; ++x) {
      int ra = a0 + ((x >> 2) << 6) + ta * 4 + (x & 3);
      float4 r0 = *(const float4*)(Ps + (size_t)ra * N + b0 + tb * 4);
      float4 r1 = *(const float4*)(Ps + (size_t)ra * N + b0 + 64 + tb * 4);
      rab[x][0] = r0.x; rab[x][1] = r0.y; rab[x][2] = r0.z; rab[x][3] = r0.w;
      rab[x][4] = r1.x; rab[x][5] = r1.y; rab[x][6] = r1.z; rab[x][7] = r1.w;
    }
  } else {
#pragma unroll
    for (int x = 0; x < 8; ++x) {
      int ra = a0 + ((x >> 2) << 6) + ta * 4 + (x & 3);
      float ma = (mrow[ra] > 0) ? 1.0f : 0.0f;
#pragma unroll
      for (int y = 0; y < 8; ++y) {
        int cbcol = b0 + ((y >> 2) << 6) + tb * 4 + (y & 3);
        float mb = (mrow[cbcol] > 0) ? 1.0f : 0.0f;
        size_t idx = ((size_t)(bb * N + ra) * N + cbcol) * RNUM + r;
        rab[x][y] = sigmoidf_(logits[idx]) * ma * mb;
      }
    }
  }

  float acc[8][8];
#pragma unroll
  for (int x = 0; x < 8; ++x)
#pragma unroll
    for (int y = 0; y < 8; ++y) acc[x][y] = 0.0f;

  for (int c0 = cbeg; c0 < cend; c0 += CT) {
    __syncthreads();
    if (USE_P) {
      // per array: 8 c4-groups x 128 rows = 1024 float4s, 4 per thread
#pragma unroll
      for (int it = 0; it < 4; ++it) {
        int f  = it * 256 + tid;
        int c4 = f & 7;
        int i  = f >> 3;
        int pc = ((((i >> 2) ^ c4) & 31) << 2) | (i & 3);
        float4 va = *(const float4*)(Ps + (size_t)(a0 + i) * N + c0 + c4 * 4);
        tA[c4 * 4 + 0][pc] = va.x;
        tA[c4 * 4 + 1][pc] = va.y;
        tA[c4 * 4 + 2][pc] = va.z;
        tA[c4 * 4 + 3][pc] = va.w;
        float4 vb = *(const float4*)(Ps + (size_t)(b0 + i) * N + c0 + c4 * 4);
        tB[c4 * 4 + 0][pc] = vb.x;
        tB[c4 * 4 + 1][pc] = vb.y;
        tB[c4 * 4 + 2][pc] = vb.z;
        tB[c4 * 4 + 3][pc] = vb.w;
      }
    } else {
#pragma unroll
      for (int it = 0; it < 16; ++it) {
        int e = it * 256 + tid;
        int c = e & 31;
        int i = e >> 5;
        int c4 = c >> 2;
        int pc = ((((i >> 2) ^ c4) & 31) << 2) | (i & 3);
        float mc = (mrow[c0 + c] > 0) ? 1.0f : 0.0f;
        {
          float mi = (mrow[a0 + i] > 0) ? 1.0f : 0.0f;
          size_t idx = ((size_t)(bb * N + a0 + i) * N + (c0 + c)) * RNUM + r;
          tA[c][pc] = sigmoidf_(logits[idx]) * mi * mc;
        }
        {
          float mi = (mrow[b0 + i] > 0) ? 1.0f : 0.0f;
          size_t idx = ((size_t)(bb * N + b0 + i) * N + (c0 + c)) * RNUM + r;
          tB[c][pc] = sigmoidf_(logits[idx]) * mi * mc;
        }
      }
    }
    __syncthreads();

#pragma unroll 2
    for (int cg = 0; cg < CT / 4; ++cg) {       // cg = swizzle key c4
      const float* pa = &tA[cg * 4][((ta ^ cg) & 31) << 2];
      const float* pb = &tB[cg * 4][((tb ^ cg) & 31) << 2];
#pragma unroll
      for (int dc = 0; dc < 4; ++dc) {
        float4 a0v = *(const float4*)(pa + dc * STRIDE);
        float4 a1v = *(const float4*)(pa + dc * STRIDE + 64);
        float4 b0v = *(const float4*)(pb + dc * STRIDE);
        float4 b1v = *(const float4*)(pb + dc * STRIDE + 64);
        float av[8] = {a0v.x, a0v.y, a0v.z, a0v.w, a1v.x, a1v.y, a1v.z, a1v.w};
        float bv[8] = {b0v.x, b0v.y, b0v.z, b0v.w, b1v.x, b1v.y, b1v.z, b1v.w};
#pragma unroll
        for (int x = 0; x < 8; ++x)
#pragma unroll
          for (int y = 0; y < 8; ++y)
            acc[x][y] += fabsf(fmaf(-av[x], bv[y], rab[x][y]));
      }
    }
  }

  float tsum = 0.0f;
#pragma unroll
  for (int x = 0; x < 8; ++x)
#pragma unroll
    for (int y = 0; y < 8; ++y) tsum += acc[x][y];

  for (int off = 32; off > 0; off >>= 1) tsum += __shfl_down(tsum, off, 64);

  const int wid = tid >> 6;
  if ((tid & 63) == 0) wsum[wid] = tsum;
  __syncthreads();
  if (tid == 0)
    atomicAdd(out, (wsum[0] + wsum[1] + wsum[2] + wsum[3]) * SCALE);
}

extern "C" void kernel_launch(void* const* d_in, const int* in_sizes, int n_in,
                              void* d_out, int out_size, void* d_ws, size_t ws_size,
                              hipStream_t stream) {
  const float* logits = (const float*)d_in[0];
  const int*   masks  = (const int*)d_in[1];
  float*       out    = (float*)d_out;

  const size_t P_BYTES = (size_t)NSLICE * N * N * sizeof(float);  // 8 MB
  const int nblocks = NCOLB + (N / TILE) * (N / TILE) * NSLICE * CSPLIT; // 528

  if (ws_size >= P_BYTES) {
    float* P = (float*)d_ws;
    prep_kernel<<<(BNUM * N * N) / 256, 256, 0, stream>>>(logits, masks, P, out);
    work_kernel<true><<<nblocks, 256, 0, stream>>>(P, logits, masks, out);
  } else {
    zero_out_kernel<<<1, 1, 0, stream>>>(out);
    work_kernel<false><<<nblocks, 256, 0, stream>>>(nullptr, logits, masks, out);
  }
}

// Round 4
// 142.613 us; speedup vs baseline: 1.5830x; 1.5830x over previous
//
#include <hip/hip_runtime.h>
#include <math.h>

#define N      512
#define RNUM   4
#define BNUM   2
#define NSLICE (RNUM * BNUM)
#define TILE   128               // (a,b) tile is 128x128, 256 threads x (8x8)
#define CT     32                // c-chunk per LDS stage
#define PAD    4
#define STRIDE (TILE + PAD)      // 132 floats
#define CSPLIT 4                 // c-split -> 512 main blocks
#define NCOLB  16                // colsum-role blocks (8 slices x 2 col-halves)
#define SCALE  0.0625f           // 1/16 = (1/2 from relu split) * (1/8 weight)

__device__ __forceinline__ float sigmoidf_(float x) {
  return 1.0f / (1.0f + __expf(-x));
}

__global__ void zero_out_kernel(float* out) { out[0] = 0.0f; }

// One thread per (b,i,j): float4 over r, writes 4 slice planes with sigmoid+mask.
// Block 0 thread 0 also zeroes the output accumulator.
__global__ __launch_bounds__(256) void prep_kernel(const float* __restrict__ logits,
                                                   const int* __restrict__ masks,
                                                   float* __restrict__ P,
                                                   float* __restrict__ out) {
  if (blockIdx.x == 0 && threadIdx.x == 0) out[0] = 0.0f;
  int t = blockIdx.x * 256 + threadIdx.x;      // 0 .. B*N*N-1
  int b = t / (N * N);
  int rem = t - b * (N * N);
  int i = rem / N;
  int j = rem - i * N;
  float4 lg = *(const float4*)(logits + (size_t)t * 4);
  float mm = ((masks[b * N + i] > 0) && (masks[b * N + j] > 0)) ? 1.0f : 0.0f;
  size_t base = (size_t)b * RNUM * N * N + rem;
  P[base + 0 * (size_t)N * N] = mm * sigmoidf_(lg.x);
  P[base + 1 * (size_t)N * N] = mm * sigmoidf_(lg.y);
  P[base + 2 * (size_t)N * N] = mm * sigmoidf_(lg.z);
  P[base + 3 * (size_t)N * N] = mm * sigmoidf_(lg.w);
}

// Work kernel, two roles by blockIdx.x:
//  bid <  NCOLB : colsum role — Sum_c csum_c*(N-csum_c)  (factorized Sum(x))
//  bid >= NCOLB : main role — Sum |rab - a_c*b_c| over the block's
//                 (slice, 128x128 (a,b) tile, c-range) via LDS-staged tiles.
// LDS layout transposed + XOR swizzle: element (c, i) at row c, col
// pcol = (((i>>2) ^ c4) & 31)*4 + (i&3), c4 = (c&31)>>2.  Writes 2-way (free),
// A-reads 2-way b128, B-reads broadcast — verified bank math, stride 132.
// Register budget note: acc is [8][2], NOT [8][8] — with acc[8][8]+rab[8][8]
// the live set exceeds the 170-VGPR cap at 3 waves/EU and the compiler spills
// to scratch (R2: 437 MB WRITE_SIZE, 2x regression).
template <bool USE_P>
__global__ __launch_bounds__(256, 3) void work_kernel(const float* __restrict__ P,
                                                      const float* __restrict__ logits,
                                                      const int* __restrict__ masks,
                                                      float* __restrict__ out) {
  __shared__ __align__(16) float tA[CT][STRIDE];
  __shared__ __align__(16) float tB[CT][STRIDE];
  __shared__ float wsum[4];

  const int tid = threadIdx.x;
  const int bid = blockIdx.x;

  if (bid < NCOLB) {
    // ---- colsum role: Sum_c csum_c * (N - csum_c) per slice ----
    const int s    = bid >> 1;
    const int half = bid & 1;
    const int c    = half * 256 + tid;
    const int bb   = s >> 2;
    const int r    = s & 3;
    float sum = 0.0f;
    if (USE_P) {
      const float* Ps = P + (size_t)s * N * N + c;
#pragma unroll 8
      for (int a = 0; a < N; ++a) sum += Ps[(size_t)a * N];
    } else {
      const int* mrow = masks + bb * N;
      float mc = (mrow[c] > 0) ? 1.0f : 0.0f;
#pragma unroll 4
      for (int a = 0; a < N; ++a) {
        float ma = (mrow[a] > 0) ? 1.0f : 0.0f;
        size_t idx = ((size_t)(bb * N + a) * N + c) * RNUM + r;
        sum += sigmoidf_(logits[idx]) * ma * mc;
      }
    }
    float v = sum * ((float)N - sum);
    for (int off = 32; off > 0; off >>= 1) v += __shfl_down(v, off, 64);
    const int wid = tid >> 6;
    if ((tid & 63) == 0) wsum[wid] = v;
    __syncthreads();
    if (tid == 0)
      atomicAdd(out, (wsum[0] + wsum[1] + wsum[2] + wsum[3]) * SCALE);
    return;
  }

  // ---- main role: Sum |rab - a_c*b_c| ----
  const int m  = bid - NCOLB;
  const int bt = m & 3;
  const int at = (m >> 2) & 3;
  const int s  = (m >> 4) & 7;
  const int cz = m >> 7;                    // 0..CSPLIT-1
  const int a0 = at * TILE;
  const int b0 = bt * TILE;
  const int bb = s >> 2;
  const int r  = s & 3;
  const int cbeg = cz * (N / CSPLIT);
  const int cend = cbeg + (N / CSPLIT);

  const int ta = tid & 15;    // a rows: a0 + ta*4 + x  and  a0 + 64 + ta*4 + x
  const int tb = tid >> 4;    // b cols: b0 + tb*4 + y  and  b0 + 64 + tb*4 + y

  const float* Ps = P + (size_t)s * N * N;
  const int* mrow = masks + bb * N;

  float rab[8][8];
  if (USE_P) {
#pragma unroll
    for (int x = 0; x < 8; ++x) {
      int ra = a0 + ((x >> 2) << 6) + ta * 4 + (x & 3);
      float4 r0 = *(const float4*)(Ps + (size_t)ra * N + b0 + tb * 4);
      float4 r1 = *(const float4*)(Ps + (size_t)ra * N + b0 + 64 + tb * 4);
      rab[x][0] = r0.x; rab[x][1] = r0.y; rab[x][2] = r0.z; rab[x][3] = r0.w;
      rab[x][4] = r1.x; rab[x][5] = r1.y; rab[x][6] = r1.z; rab[x][7] = r1.w;
    }
  } else {
#pragma unroll
    for (int x = 0; x < 8; ++x) {
      int ra = a0 + ((x >> 2) << 6) + ta * 4 + (x & 3);
      float ma = (mrow[ra] > 0) ? 1.0f : 0.0f;
#pragma unroll
      for (int y = 0; y < 8; ++y) {
        int cbcol = b0 + ((y >> 2) << 6) + tb * 4 + (y & 3);
        float mb = (mrow[cbcol] > 0) ? 1.0f : 0.0f;
        size_t idx = ((size_t)(bb * N + ra) * N + cbcol) * RNUM + r;
        rab[x][y] = sigmoidf_(logits[idx]) * ma * mb;
      }
    }
  }

  float acc[8][2];
#pragma unroll
  for (int x = 0; x < 8; ++x) { acc[x][0] = 0.0f; acc[x][1] = 0.0f; }

  for (int c0 = cbeg; c0 < cend; c0 += CT) {
    __syncthreads();
    if (USE_P) {
      // per array: 8 c4-groups x 128 rows = 1024 float4s, 4 per thread
#pragma unroll
      for (int it = 0; it < 4; ++it) {
        int f  = it * 256 + tid;
        int c4 = f & 7;
        int i  = f >> 3;
        int pc = ((((i >> 2) ^ c4) & 31) << 2) | (i & 3);
        float4 va = *(const float4*)(Ps + (size_t)(a0 + i) * N + c0 + c4 * 4);
        tA[c4 * 4 + 0][pc] = va.x;
        tA[c4 * 4 + 1][pc] = va.y;
        tA[c4 * 4 + 2][pc] = va.z;
        tA[c4 * 4 + 3][pc] = va.w;
        float4 vb = *(const float4*)(Ps + (size_t)(b0 + i) * N + c0 + c4 * 4);
        tB[c4 * 4 + 0][pc] = vb.x;
        tB[c4 * 4 + 1][pc] = vb.y;
        tB[c4 * 4 + 2][pc] = vb.z;
        tB[c4 * 4 + 3][pc] = vb.w;
      }
    } else {
#pragma unroll
      for (int it = 0; it < 16; ++it) {
        int e = it * 256 + tid;
        int c = e & 31;
        int i = e >> 5;
        int c4 = c >> 2;
        int pc = ((((i >> 2) ^ c4) & 31) << 2) | (i & 3);
        float mc = (mrow[c0 + c] > 0) ? 1.0f : 0.0f;
        {
          float mi = (mrow[a0 + i] > 0) ? 1.0f : 0.0f;
          size_t idx = ((size_t)(bb * N + a0 + i) * N + (c0 + c)) * RNUM + r;
          tA[c][pc] = sigmoidf_(logits[idx]) * mi * mc;
        }
        {
          float mi = (mrow[b0 + i] > 0) ? 1.0f : 0.0f;
          size_t idx = ((size_t)(bb * N + b0 + i) * N + (c0 + c)) * RNUM + r;
          tB[c][pc] = sigmoidf_(logits[idx]) * mi * mc;
        }
      }
    }
    __syncthreads();

#pragma unroll 2
    for (int cg = 0; cg < CT / 4; ++cg) {       // cg = swizzle key c4
      const float* pa = &tA[cg * 4][((ta ^ cg) & 31) << 2];
      const float* pb = &tB[cg * 4][((tb ^ cg) & 31) << 2];
#pragma unroll
      for (int dc = 0; dc < 4; ++dc) {
        float4 a0v = *(const float4*)(pa + dc * STRIDE);
        float4 a1v = *(const float4*)(pa + dc * STRIDE + 64);
        float4 b0v = *(const float4*)(pb + dc * STRIDE);
        float4 b1v = *(const float4*)(pb + dc * STRIDE + 64);
        float av[8] = {a0v.x, a0v.y, a0v.z, a0v.w, a1v.x, a1v.y, a1v.z, a1v.w};
        float bv[8] = {b0v.x, b0v.y, b0v.z, b0v.w, b1v.x, b1v.y, b1v.z, b1v.w};
#pragma unroll
        for (int x = 0; x < 8; ++x) {
#pragma unroll
          for (int y = 0; y < 4; ++y)
            acc[x][0] += fabsf(fmaf(-av[x], bv[y], rab[x][y]));
#pragma unroll
          for (int y = 4; y < 8; ++y)
            acc[x][1] += fabsf(fmaf(-av[x], bv[y], rab[x][y]));
        }
      }
    }
  }

  float tsum = 0.0f;
#pragma unroll
  for (int x = 0; x < 8; ++x) tsum += acc[x][0] + acc[x][1];

  for (int off = 32; off > 0; off >>= 1) tsum += __shfl_down(tsum, off, 64);

  const int wid = tid >> 6;
  if ((tid & 63) == 0) wsum[wid] = tsum;
  __syncthreads();
  if (tid == 0)
    atomicAdd(out, (wsum[0] + wsum[1] + wsum[2] + wsum[3]) * SCALE);
}

extern "C" void kernel_launch(void* const* d_in, const int* in_sizes, int n_in,
                              void* d_out, int out_size, void* d_ws, size_t ws_size,
                              hipStream_t stream) {
  const float* logits = (const float*)d_in[0];
  const int*   masks  = (const int*)d_in[1];
  float*       out    = (float*)d_out;

  const size_t P_BYTES = (size_t)NSLICE * N * N * sizeof(float);  // 8 MB
  const int nblocks = NCOLB + (N / TILE) * (N / TILE) * NSLICE * CSPLIT; // 528

  if (ws_size >= P_BYTES) {
    float* P = (float*)d_ws;
    prep_kernel<<<(BNUM * N * N) / 256, 256, 0, stream>>>(logits, masks, P, out);
    work_kernel<true><<<nblocks, 256, 0, stream>>>(P, logits, masks, out);
  } else {
    zero_out_kernel<<<1, 1, 0, stream>>>(out);
    work_kernel<false><<<nblocks, 256, 0, stream>>>(nullptr, logits, masks, out);
  }
}

// Round 5
// 139.058 us; speedup vs baseline: 1.6235x; 1.0256x over previous
//
#include <hip/hip_runtime.h>
#include <math.h>

#define N      512
#define RNUM   4
#define BNUM   2
#define NSLICE (RNUM * BNUM)
#define TILE   128               // (a,b) tile is 128x128, 256 threads x (8x8)
#define CT     64                // c-chunk per LDS stage (2 barriers / 64 c)
#define PAD    4
#define STRIDE (TILE + PAD)      // 132 floats
#define CSPLIT 4                 // c-split -> 512 main blocks
#define NCOLB  16                // colsum-role blocks (8 slices x 2 col-halves)
#define SCALE  0.0625f           // 1/16 = (1/2 from relu split) * (1/8 weight)

__device__ __forceinline__ float sigmoidf_(float x) {
  return 1.0f / (1.0f + __expf(-x));
}

__global__ void zero_out_kernel(float* out) { out[0] = 0.0f; }

// One thread per (b,i,j): float4 over r, writes 4 slice planes with sigmoid+mask.
// Block 0 thread 0 also zeroes the output accumulator.
__global__ __launch_bounds__(256) void prep_kernel(const float* __restrict__ logits,
                                                   const int* __restrict__ masks,
                                                   float* __restrict__ P,
                                                   float* __restrict__ out) {
  if (blockIdx.x == 0 && threadIdx.x == 0) out[0] = 0.0f;
  int t = blockIdx.x * 256 + threadIdx.x;      // 0 .. B*N*N-1
  int b = t / (N * N);
  int rem = t - b * (N * N);
  int i = rem / N;
  int j = rem - i * N;
  float4 lg = *(const float4*)(logits + (size_t)t * 4);
  float mm = ((masks[b * N + i] > 0) && (masks[b * N + j] > 0)) ? 1.0f : 0.0f;
  size_t base = (size_t)b * RNUM * N * N + rem;
  P[base + 0 * (size_t)N * N] = mm * sigmoidf_(lg.x);
  P[base + 1 * (size_t)N * N] = mm * sigmoidf_(lg.y);
  P[base + 2 * (size_t)N * N] = mm * sigmoidf_(lg.z);
  P[base + 3 * (size_t)N * N] = mm * sigmoidf_(lg.w);
}

// Work kernel, two roles by blockIdx.x:
//  bid <  NCOLB : colsum role — Sum_c csum_c*(N-csum_c)  (factorized Sum(x))
//  bid >= NCOLB : main role — Sum |rab - a_c*b_c| over the block's
//                 (slice, 128x128 (a,b) tile, c-range) via LDS-staged tiles.
// LDS layout transposed + XOR swizzle: element (c, i) at row c, col
// pcol = (((i>>2) ^ c4) & 31)*4 + (i&3), c4 = (c&31)>>2.  Writes 2-way (free),
// A-reads 2-way b128, B-reads broadcast — verified bank math, stride 132.
// Register budget notes:
//  - acc is [8][2], NOT [8][8]: with both 8x8 arrays live the set blows past
//    any reasonable cap and spills to scratch (R2: 437 MB WRITE_SIZE, 2x).
//  - __launch_bounds__(256, 2): at (256,3) the allocator pinned 84 arch VGPRs
//    (~6 waves/EU heuristic) and shuffled rab through AGPR/scratch (R3:
//    21.7 MB WRITE_SIZE, VALU-issue 2.2x the 2-inst/elem floor). 2 waves/EU
//    grants 256 VGPRs; live set ~130 fits in arch VGPRs. 8 waves/CU matches
//    the 2-blocks/CU grid exactly.
template <bool USE_P>
__global__ __launch_bounds__(256, 2) void work_kernel(const float* __restrict__ P,
                                                      const float* __restrict__ logits,
                                                      const int* __restrict__ masks,
                                                      float* __restrict__ out) {
  __shared__ __align__(16) float tA[CT][STRIDE];
  __shared__ __align__(16) float tB[CT][STRIDE];
  __shared__ float wsum[4];

  const int tid = threadIdx.x;
  const int bid = blockIdx.x;

  if (bid < NCOLB) {
    // ---- colsum role: Sum_c csum_c * (N - csum_c) per slice ----
    const int s    = bid >> 1;
    const int half = bid & 1;
    const int c    = half * 256 + tid;
    const int bb   = s >> 2;
    const int r    = s & 3;
    float sum = 0.0f;
    if (USE_P) {
      const float* Ps = P + (size_t)s * N * N + c;
#pragma unroll 8
      for (int a = 0; a < N; ++a) sum += Ps[(size_t)a * N];
    } else {
      const int* mrow = masks + bb * N;
      float mc = (mrow[c] > 0) ? 1.0f : 0.0f;
#pragma unroll 4
      for (int a = 0; a < N; ++a) {
        float ma = (mrow[a] > 0) ? 1.0f : 0.0f;
        size_t idx = ((size_t)(bb * N + a) * N + c) * RNUM + r;
        sum += sigmoidf_(logits[idx]) * ma * mc;
      }
    }
    float v = sum * ((float)N - sum);
    for (int off = 32; off > 0; off >>= 1) v += __shfl_down(v, off, 64);
    const int wid = tid >> 6;
    if ((tid & 63) == 0) wsum[wid] = v;
    __syncthreads();
    if (tid == 0)
      atomicAdd(out, (wsum[0] + wsum[1] + wsum[2] + wsum[3]) * SCALE);
    return;
  }

  // ---- main role: Sum |rab - a_c*b_c| ----
  const int m  = bid - NCOLB;
  const int bt = m & 3;
  const int at = (m >> 2) & 3;
  const int s  = (m >> 4) & 7;
  const int cz = m >> 7;                    // 0..CSPLIT-1
  const int a0 = at * TILE;
  const int b0 = bt * TILE;
  const int bb = s >> 2;
  const int r  = s & 3;
  const int cbeg = cz * (N / CSPLIT);
  const int cend = cbeg + (N / CSPLIT);

  const int ta = tid & 15;    // a rows: a0 + ta*4 + x  and  a0 + 64 + ta*4 + x
  const int tb = tid >> 4;    // b cols: b0 + tb*4 + y  and  b0 + 64 + tb*4 + y

  const float* Ps = P + (size_t)s * N * N;
  const int* mrow = masks + bb * N;

  float rab[8][8];
  if (USE_P) {
#pragma unroll
    for (int x = 0; x < 8; ++x) {
      int ra = a0 + ((x >> 2) << 6) + ta * 4 + (x & 3);
      float4 r0 = *(const float4*)(Ps + (size_t)ra * N + b0 + tb * 4);
      float4 r1 = *(const float4*)(Ps + (size_t)ra * N + b0 + 64 + tb * 4);
      rab[x][0] = r0.x; rab[x][1] = r0.y; rab[x][2] = r0.z; rab[x][3] = r0.w;
      rab[x][4] = r1.x; rab[x][5] = r1.y; rab[x][6] = r1.z; rab[x][7] = r1.w;
    }
  } else {
#pragma unroll
    for (int x = 0; x < 8; ++x) {
      int ra = a0 + ((x >> 2) << 6) + ta * 4 + (x & 3);
      float ma = (mrow[ra] > 0) ? 1.0f : 0.0f;
#pragma unroll
      for (int y = 0; y < 8; ++y) {
        int cbcol = b0 + ((y >> 2) << 6) + tb * 4 + (y & 3);
        float mb = (mrow[cbcol] > 0) ? 1.0f : 0.0f;
        size_t idx = ((size_t)(bb * N + ra) * N + cbcol) * RNUM + r;
        rab[x][y] = sigmoidf_(logits[idx]) * ma * mb;
      }
    }
  }

  float acc[8][2];
#pragma unroll
  for (int x = 0; x < 8; ++x) { acc[x][0] = 0.0f; acc[x][1] = 0.0f; }

  for (int c0 = cbeg; c0 < cend; c0 += CT) {
    __syncthreads();
    if (USE_P) {
      // per array: 16 c4-groups x 128 rows = 2048 float4s, 8 per thread
#pragma unroll
      for (int it = 0; it < 8; ++it) {
        int f  = it * 256 + tid;
        int c4 = f & 15;                      // c4 = c>>2 within chunk
        int i  = f >> 4;
        int pc = ((((i >> 2) ^ c4) & 31) << 2) | (i & 3);
        float4 va = *(const float4*)(Ps + (size_t)(a0 + i) * N + c0 + c4 * 4);
        tA[c4 * 4 + 0][pc] = va.x;
        tA[c4 * 4 + 1][pc] = va.y;
        tA[c4 * 4 + 2][pc] = va.z;
        tA[c4 * 4 + 3][pc] = va.w;
        float4 vb = *(const float4*)(Ps + (size_t)(b0 + i) * N + c0 + c4 * 4);
        tB[c4 * 4 + 0][pc] = vb.x;
        tB[c4 * 4 + 1][pc] = vb.y;
        tB[c4 * 4 + 2][pc] = vb.z;
        tB[c4 * 4 + 3][pc] = vb.w;
      }
    } else {
#pragma unroll
      for (int it = 0; it < 32; ++it) {
        int e = it * 256 + tid;
        int c = e & 63;
        int i = e >> 6;
        int c4 = (c & 31) >> 2;               // swizzle key uses c&31 grouping
        int pc = ((((i >> 2) ^ ((c >> 2) & 31)) & 31) << 2) | (i & 3);
        (void)c4;
        float mc = (mrow[c0 + c] > 0) ? 1.0f : 0.0f;
        {
          float mi = (mrow[a0 + i] > 0) ? 1.0f : 0.0f;
          size_t idx = ((size_t)(bb * N + a0 + i) * N + (c0 + c)) * RNUM + r;
          tA[c][pc] = sigmoidf_(logits[idx]) * mi * mc;
        }
        {
          float mi = (mrow[b0 + i] > 0) ? 1.0f : 0.0f;
          size_t idx = ((size_t)(bb * N + b0 + i) * N + (c0 + c)) * RNUM + r;
          tB[c][pc] = sigmoidf_(logits[idx]) * mi * mc;
        }
      }
    }
    __syncthreads();

#pragma unroll 2
    for (int cg = 0; cg < CT / 4; ++cg) {       // cg = swizzle key c4
      const float* pa = &tA[cg * 4][((ta ^ cg) & 31) << 2];
      const float* pb = &tB[cg * 4][((tb ^ cg) & 31) << 2];
#pragma unroll
      for (int dc = 0; dc < 4; ++dc) {
        float4 a0v = *(const float4*)(pa + dc * STRIDE);
        float4 a1v = *(const float4*)(pa + dc * STRIDE + 64);
        float4 b0v = *(const float4*)(pb + dc * STRIDE);
        float4 b1v = *(const float4*)(pb + dc * STRIDE + 64);
        float av[8] = {a0v.x, a0v.y, a0v.z, a0v.w, a1v.x, a1v.y, a1v.z, a1v.w};
        float bv[8] = {b0v.x, b0v.y, b0v.z, b0v.w, b1v.x, b1v.y, b1v.z, b1v.w};
#pragma unroll
        for (int x = 0; x < 8; ++x) {
#pragma unroll
          for (int y = 0; y < 4; ++y) {
            float t = fmaf(-av[x], bv[y], rab[x][y]);
            acc[x][0] += fabsf(t);
          }
#pragma unroll
          for (int y = 4; y < 8; ++y) {
            float t = fmaf(-av[x], bv[y], rab[x][y]);
            acc[x][1] += fabsf(t);
          }
        }
      }
    }
  }

  float tsum = 0.0f;
#pragma unroll
  for (int x = 0; x < 8; ++x) tsum += acc[x][0] + acc[x][1];

  for (int off = 32; off > 0; off >>= 1) tsum += __shfl_down(tsum, off, 64);

  const int wid = tid >> 6;
  if ((tid & 63) == 0) wsum[wid] = tsum;
  __syncthreads();
  if (tid == 0)
    atomicAdd(out, (wsum[0] + wsum[1] + wsum[2] + wsum[3]) * SCALE);
}

extern "C" void kernel_launch(void* const* d_in, const int* in_sizes, int n_in,
                              void* d_out, int out_size, void* d_ws, size_t ws_size,
                              hipStream_t stream) {
  const float* logits = (const float*)d_in[0];
  const int*   masks  = (const int*)d_in[1];
  float*       out    = (float*)d_out;

  const size_t P_BYTES = (size_t)NSLICE * N * N * sizeof(float);  // 8 MB
  const int nblocks = NCOLB + (N / TILE) * (N / TILE) * NSLICE * CSPLIT; // 528

  if (ws_size >= P_BYTES) {
    float* P = (float*)d_ws;
    prep_kernel<<<(BNUM * N * N) / 256, 256, 0, stream>>>(logits, masks, P, out);
    work_kernel<true><<<nblocks, 256, 0, stream>>>(P, logits, masks, out);
  } else {
    zero_out_kernel<<<1, 1, 0, stream>>>(out);
    work_kernel<false><<<nblocks, 256, 0, stream>>>(nullptr, logits, masks, out);
  }
}

// Round 7
// 115.761 us; speedup vs baseline: 1.9502x; 1.2013x over previous
//
#include <hip/hip_runtime.h>
#include <math.h>

#define N      512
#define RNUM   4
#define BNUM   2
#define NSLICE (RNUM * BNUM)
#define TILE   128               // (a,b) tile 128x128, 256 threads x (8x8)
#define CT     32                // c-chunk per LDS stage (f16 tiles)
#define LSTR   136               // f16 row stride (272 B) - bank-verified
#define CSPLIT 8                 // c-split -> 1024 main blocks
#define NCOLB  16                // colsum-role blocks (8 slices x 2 halves)
#define SCALE  0.0625f           // (1/2 relu-split) * (1/8 weight/(R*B))

typedef _Float16 half2_t __attribute__((ext_vector_type(2)));

__device__ __forceinline__ unsigned int h2u(half2_t h) {
  return __builtin_bit_cast(unsigned int, h);
}
__device__ __forceinline__ half2_t u2h(unsigned int u) {
  return __builtin_bit_cast(half2_t, u);
}

#if __has_builtin(__builtin_amdgcn_fdot2)
__device__ __forceinline__ float fdot2_(half2_t a, half2_t b, float c) {
  return __builtin_amdgcn_fdot2(a, b, c, false);
}
#else
__device__ __forceinline__ float fdot2_(half2_t a, half2_t b, float c) {
  return c + (float)a.x * (float)b.x + (float)a.y * (float)b.y;
}
#endif

__device__ __forceinline__ float sigmoidf_(float x) {
  return 1.0f / (1.0f + __expf(-x));
}

__global__ void zero_out_kernel(float* out) { out[0] = 0.0f; }

// One thread per (b,i,j): reads float4 over r, writes 4 f16 slice planes
// P[s][i][j] (row-major, mask+sigmoid folded). Coalesced 2B stores (lanes =
// consecutive j). Block 0 thread 0 zeroes the output accumulator.
__global__ __launch_bounds__(256) void prep_f16_kernel(const float* __restrict__ logits,
                                                       const int* __restrict__ masks,
                                                       _Float16* __restrict__ P,
                                                       float* __restrict__ out) {
  if (blockIdx.x == 0 && threadIdx.x == 0) out[0] = 0.0f;
  int t = blockIdx.x * 256 + threadIdx.x;      // 0 .. B*N*N-1
  int b = t >> 18;                              // / (N*N)
  int rem = t & (N * N - 1);
  int i = rem >> 9;
  int j = rem & (N - 1);
  float4 lg = *(const float4*)(logits + (size_t)t * 4);
  float mm = ((masks[b * N + i] > 0) && (masks[b * N + j] > 0)) ? 1.0f : 0.0f;
  size_t base = (size_t)b * RNUM * N * N + rem;
  P[base + 0 * (size_t)N * N] = (_Float16)(mm * sigmoidf_(lg.x));
  P[base + 1 * (size_t)N * N] = (_Float16)(mm * sigmoidf_(lg.y));
  P[base + 2 * (size_t)N * N] = (_Float16)(mm * sigmoidf_(lg.z));
  P[base + 3 * (size_t)N * N] = (_Float16)(mm * sigmoidf_(lg.w));
}

// Work kernel (f16 path), two roles by blockIdx.x:
//  bid <  NCOLB : colsum role — Sum_c csum_c*(N-csum_c)  (factorized Sum(x))
//  bid >= NCOLB : main role — Sum |rab - a_c*b_c| via packed f16:
//    per 2 elements: v_pk_fma_f16 + v_and (packed abs) + v_dot2_f32_f16
//    = 1.5 VALU inst/elem (vs 2.0 f32), f32 accumulation via dot2.
// LDS tiles [c][x] f16, stride LSTR=136 (272 B): per-c reads are 16 distinct
// 8B addrs covering all 32 banks with 4-lane broadcast (conflict-free);
// staging b16 writes are 2-lane same-dword (free).
// R5 BUG (fixed here): staging read only 32 B (16 c-values) per thread but
// CT=32 needs 64 B — LDS rows 16..31 were uninitialized -> NaN output.
__global__ __launch_bounds__(256, 2) void work_f16_kernel(const _Float16* __restrict__ P,
                                                          float* __restrict__ out) {
  __shared__ _Float16 tA[CT][LSTR];
  __shared__ _Float16 tB[CT][LSTR];
  __shared__ float wsum[4];

  const int tid = threadIdx.x;
  const int bid = blockIdx.x;

  if (bid < NCOLB) {
    // ---- colsum role ----
    const int s    = bid >> 1;
    const int half = bid & 1;
    const int c    = half * 256 + tid;
    const _Float16* col = P + (size_t)s * N * N + c;
    float sum = 0.0f;
#pragma unroll 8
    for (int a = 0; a < N; ++a) sum += (float)col[(size_t)a * N];
    float v = sum * ((float)N - sum);
    for (int off = 32; off > 0; off >>= 1) v += __shfl_down(v, off, 64);
    const int wid = tid >> 6;
    if ((tid & 63) == 0) wsum[wid] = v;
    __syncthreads();
    if (tid == 0)
      atomicAdd(out, (wsum[0] + wsum[1] + wsum[2] + wsum[3]) * SCALE);
    return;
  }

  // ---- main role ----
  const int m  = bid - NCOLB;
  const int bt = m & 3;
  const int at = (m >> 2) & 3;
  const int s  = (m >> 4) & 7;
  const int cz = m >> 7;                    // 0..CSPLIT-1
  const int a0 = at * TILE;
  const int b0 = bt * TILE;
  const int cbeg = cz * (N / CSPLIT);       // 64-wide c-range = 2 chunks
  const int cend = cbeg + (N / CSPLIT);

  const int ta = tid & 15;    // a cols (tile-local): ta*4+0..3 and 64+ta*4+0..3
  const int tb = tid >> 4;    // b cols (tile-local): tb*4+0..3 and 64+tb*4+0..3

  const _Float16* Ph = P + (size_t)s * N * N;

  // rab as f16 pairs over y: rab2[x][yp] = {rab[x][2yp], rab[x][2yp+1]}
  half2_t rab2[8][4];
#pragma unroll
  for (int x = 0; x < 8; ++x) {
    int ga = a0 + ((x >> 2) << 6) + ta * 4 + (x & 3);
    uint2 u0 = *(const uint2*)(Ph + (size_t)ga * N + b0 + tb * 4);
    uint2 u1 = *(const uint2*)(Ph + (size_t)ga * N + b0 + 64 + tb * 4);
    rab2[x][0] = u2h(u0.x); rab2[x][1] = u2h(u0.y);
    rab2[x][2] = u2h(u1.x); rab2[x][3] = u2h(u1.y);
  }

  float acc[8];
#pragma unroll
  for (int x = 0; x < 8; ++x) acc[x] = 0.0f;

  const half2_t kOne = {(_Float16)1.0f, (_Float16)1.0f};

  // staging role for this thread: one row of A-tile or B-tile
  const int sx   = tid & 127;               // tile-local column it stages
  const int sarr = tid >> 7;                // 0 -> A, 1 -> B
  const _Float16* srow = Ph + (size_t)((sarr ? b0 : a0) + sx) * N;
  _Float16* dcol = sarr ? &tB[0][sx] : &tA[0][sx];

  for (int c0 = cbeg; c0 < cend; c0 += CT) {
    __syncthreads();
    {
      // read 32 c-values (64 B = 4 x uint4) for row sx, transpose into LDS
      // column sx (all CT=32 rows written — R5 wrote only 16).
      const uint4* src = (const uint4*)(srow + c0);
      uint4 q0 = src[0];
      uint4 q1 = src[1];
      uint4 q2 = src[2];
      uint4 q3 = src[3];
      unsigned int w[16] = {q0.x, q0.y, q0.z, q0.w, q1.x, q1.y, q1.z, q1.w,
                            q2.x, q2.y, q2.z, q2.w, q3.x, q3.y, q3.z, q3.w};
      union { unsigned int u32; _Float16 h[2]; } cv;
#pragma unroll
      for (int k = 0; k < 16; ++k) {
        cv.u32 = w[k];
        dcol[(size_t)(2 * k) * LSTR]     = cv.h[0];
        dcol[(size_t)(2 * k + 1) * LSTR] = cv.h[1];
      }
    }
    __syncthreads();

#pragma unroll 4
    for (int c = 0; c < CT; ++c) {
      uint2 ua0 = *(const uint2*)&tA[c][ta * 4];
      uint2 ua1 = *(const uint2*)&tA[c][64 + ta * 4];
      uint2 ub0 = *(const uint2*)&tB[c][tb * 4];
      uint2 ub1 = *(const uint2*)&tB[c][64 + tb * 4];
      half2_t av[4] = {u2h(ua0.x), u2h(ua0.y), u2h(ua1.x), u2h(ua1.y)};
      half2_t bv[4] = {u2h(ub0.x), u2h(ub0.y), u2h(ub1.x), u2h(ub1.y)};
#pragma unroll
      for (int x = 0; x < 8; ++x) {
        _Float16 as = (x & 1) ? av[x >> 1].y : av[x >> 1].x;
        half2_t asp = {as, as};
        float a_ = acc[x];
#pragma unroll
        for (int yp = 0; yp < 4; ++yp) {
          half2_t t2 = rab2[x][yp] - asp * bv[yp];     // v_pk_fma_f16 (neg)
          half2_t p2 = u2h(h2u(t2) & 0x7FFF7FFFu);     // packed |t|
          a_ = fdot2_(p2, kOne, a_);                   // f32 accumulate
        }
        acc[x] = a_;
      }
    }
  }

  float tsum = 0.0f;
#pragma unroll
  for (int x = 0; x < 8; ++x) tsum += acc[x];

  for (int off = 32; off > 0; off >>= 1) tsum += __shfl_down(tsum, off, 64);

  const int wid = tid >> 6;
  if ((tid & 63) == 0) wsum[wid] = tsum;
  __syncthreads();
  if (tid == 0)
    atomicAdd(out, (wsum[0] + wsum[1] + wsum[2] + wsum[3]) * SCALE);
}

// ---------------- f32 fallback (no workspace): R4 structure ----------------
#define FCT    64
#define FSTR   132
#define FCSPL  4

__global__ __launch_bounds__(256, 2) void work_f32_fallback(const float* __restrict__ logits,
                                                            const int* __restrict__ masks,
                                                            float* __restrict__ out) {
  __shared__ __align__(16) float tA[FCT][FSTR];
  __shared__ __align__(16) float tB[FCT][FSTR];
  __shared__ float wsum[4];

  const int tid = threadIdx.x;
  const int bid = blockIdx.x;

  if (bid < NCOLB) {
    const int s    = bid >> 1;
    const int half = bid & 1;
    const int c    = half * 256 + tid;
    const int bb   = s >> 2;
    const int r    = s & 3;
    const int* mrow = masks + bb * N;
    float mc = (mrow[c] > 0) ? 1.0f : 0.0f;
    float sum = 0.0f;
#pragma unroll 4
    for (int a = 0; a < N; ++a) {
      float ma = (mrow[a] > 0) ? 1.0f : 0.0f;
      size_t idx = ((size_t)(bb * N + a) * N + c) * RNUM + r;
      sum += sigmoidf_(logits[idx]) * ma * mc;
    }
    float v = sum * ((float)N - sum);
    for (int off = 32; off > 0; off >>= 1) v += __shfl_down(v, off, 64);
    const int wid = tid >> 6;
    if ((tid & 63) == 0) wsum[wid] = v;
    __syncthreads();
    if (tid == 0)
      atomicAdd(out, (wsum[0] + wsum[1] + wsum[2] + wsum[3]) * SCALE);
    return;
  }

  const int m  = bid - NCOLB;
  const int bt = m & 3;
  const int at = (m >> 2) & 3;
  const int s  = (m >> 4) & 7;
  const int cz = m >> 7;
  const int a0 = at * TILE;
  const int b0 = bt * TILE;
  const int bb = s >> 2;
  const int r  = s & 3;
  const int cbeg = cz * (N / FCSPL);
  const int cend = cbeg + (N / FCSPL);

  const int ta = tid & 15;
  const int tb = tid >> 4;
  const int* mrow = masks + bb * N;

  float rab[8][8];
#pragma unroll
  for (int x = 0; x < 8; ++x) {
    int ra = a0 + ((x >> 2) << 6) + ta * 4 + (x & 3);
    float ma = (mrow[ra] > 0) ? 1.0f : 0.0f;
#pragma unroll
    for (int y = 0; y < 8; ++y) {
      int cb = b0 + ((y >> 2) << 6) + tb * 4 + (y & 3);
      float mb = (mrow[cb] > 0) ? 1.0f : 0.0f;
      size_t idx = ((size_t)(bb * N + ra) * N + cb) * RNUM + r;
      rab[x][y] = sigmoidf_(logits[idx]) * ma * mb;
    }
  }

  float acc[8][2];
#pragma unroll
  for (int x = 0; x < 8; ++x) { acc[x][0] = 0.0f; acc[x][1] = 0.0f; }

  for (int c0 = cbeg; c0 < cend; c0 += FCT) {
    __syncthreads();
#pragma unroll
    for (int it = 0; it < 32; ++it) {
      int e = it * 256 + tid;
      int c = e & 63;
      int i = e >> 6;
      int pc = ((((i >> 2) ^ ((c >> 2) & 31)) & 31) << 2) | (i & 3);
      float mc = (mrow[c0 + c] > 0) ? 1.0f : 0.0f;
      {
        float mi = (mrow[a0 + i] > 0) ? 1.0f : 0.0f;
        size_t idx = ((size_t)(bb * N + a0 + i) * N + (c0 + c)) * RNUM + r;
        tA[c][pc] = sigmoidf_(logits[idx]) * mi * mc;
      }
      {
        float mi = (mrow[b0 + i] > 0) ? 1.0f : 0.0f;
        size_t idx = ((size_t)(bb * N + b0 + i) * N + (c0 + c)) * RNUM + r;
        tB[c][pc] = sigmoidf_(logits[idx]) * mi * mc;
      }
    }
    __syncthreads();

#pragma unroll 2
    for (int cg = 0; cg < FCT / 4; ++cg) {
      const float* pa = &tA[cg * 4][((ta ^ cg) & 31) << 2];
      const float* pb = &tB[cg * 4][((tb ^ cg) & 31) << 2];
#pragma unroll
      for (int dc = 0; dc < 4; ++dc) {
        float4 a0v = *(const float4*)(pa + dc * FSTR);
        float4 a1v = *(const float4*)(pa + dc * FSTR + 64);
        float4 b0v = *(const float4*)(pb + dc * FSTR);
        float4 b1v = *(const float4*)(pb + dc * FSTR + 64);
        float avv[8] = {a0v.x, a0v.y, a0v.z, a0v.w, a1v.x, a1v.y, a1v.z, a1v.w};
        float bvv[8] = {b0v.x, b0v.y, b0v.z, b0v.w, b1v.x, b1v.y, b1v.z, b1v.w};
#pragma unroll
        for (int x = 0; x < 8; ++x) {
#pragma unroll
          for (int y = 0; y < 4; ++y)
            acc[x][0] += fabsf(fmaf(-avv[x], bvv[y], rab[x][y]));
#pragma unroll
          for (int y = 4; y < 8; ++y)
            acc[x][1] += fabsf(fmaf(-avv[x], bvv[y], rab[x][y]));
        }
      }
    }
  }

  float tsum = 0.0f;
#pragma unroll
  for (int x = 0; x < 8; ++x) tsum += acc[x][0] + acc[x][1];
  for (int off = 32; off > 0; off >>= 1) tsum += __shfl_down(tsum, off, 64);
  const int wid = tid >> 6;
  if ((tid & 63) == 0) wsum[wid] = tsum;
  __syncthreads();
  if (tid == 0)
    atomicAdd(out, (wsum[0] + wsum[1] + wsum[2] + wsum[3]) * SCALE);
}

extern "C" void kernel_launch(void* const* d_in, const int* in_sizes, int n_in,
                              void* d_out, int out_size, void* d_ws, size_t ws_size,
                              hipStream_t stream) {
  const float* logits = (const float*)d_in[0];
  const int*   masks  = (const int*)d_in[1];
  float*       out    = (float*)d_out;

  const size_t P_BYTES = (size_t)NSLICE * N * N * sizeof(_Float16);  // 4 MB

  if (ws_size >= P_BYTES) {
    _Float16* P = (_Float16*)d_ws;
    prep_f16_kernel<<<(BNUM * N * N) / 256, 256, 0, stream>>>(logits, masks, P, out);
    const int nblocks = NCOLB + 4 * 4 * NSLICE * CSPLIT;  // 16 + 1024
    work_f16_kernel<<<nblocks, 256, 0, stream>>>(P, out);
  } else {
    zero_out_kernel<<<1, 1, 0, stream>>>(out);
    const int nblocks = NCOLB + 4 * 4 * NSLICE * FCSPL;   // 16 + 512
    work_f32_fallback<<<nblocks, 256, 0, stream>>>(logits, masks, out);
  }
}

// Round 9
// 114.275 us; speedup vs baseline: 1.9756x; 1.0130x over previous
//
#include <hip/hip_runtime.h>
#include <math.h>

#define N      512
#define RNUM   4
#define BNUM   2
#define NSLICE (RNUM * BNUM)
#define TILE   128               // (a,b) tile 128x128, 256 threads x (8x8)
#define CT     32                // c-chunk per LDS stage (f16 tiles)
#define LSTR   136               // f16 row stride (272 B) - bank-verified
#define CSPLIT 16                // c-split -> 2048 main blocks (~8/CU)
#define NCOLB  16                // colsum-role blocks (8 slices x 2 halves)
#define SCALE  0.0625f           // (1/2 relu-split) * (1/8 weight/(R*B))

typedef _Float16 half2_t __attribute__((ext_vector_type(2)));

__device__ __forceinline__ unsigned int h2u(half2_t h) {
  return __builtin_bit_cast(unsigned int, h);
}
__device__ __forceinline__ half2_t u2h(unsigned int u) {
  return __builtin_bit_cast(half2_t, u);
}

#if __has_builtin(__builtin_amdgcn_fdot2)
__device__ __forceinline__ float fdot2_(half2_t a, half2_t b, float c) {
  return __builtin_amdgcn_fdot2(a, b, c, false);
}
#else
__device__ __forceinline__ float fdot2_(half2_t a, half2_t b, float c) {
  return c + (float)a.x * (float)b.x + (float)a.y * (float)b.y;
}
#endif

__device__ __forceinline__ float sigmoidf_(float x) {
  return 1.0f / (1.0f + __expf(-x));
}

__global__ void zero_out_kernel(float* out) { out[0] = 0.0f; }

// One thread per (b,i,j): reads float4 over r, writes 4 f16 slice planes
// P[s][i][j] (row-major, mask+sigmoid folded). Coalesced 2B stores.
// Block 0 thread 0 zeroes the output accumulator.
__global__ __launch_bounds__(256) void prep_f16_kernel(const float* __restrict__ logits,
                                                       const int* __restrict__ masks,
                                                       _Float16* __restrict__ P,
                                                       float* __restrict__ out) {
  if (blockIdx.x == 0 && threadIdx.x == 0) out[0] = 0.0f;
  int t = blockIdx.x * 256 + threadIdx.x;      // 0 .. B*N*N-1
  int b = t >> 18;                              // / (N*N)
  int rem = t & (N * N - 1);
  int i = rem >> 9;
  int j = rem & (N - 1);
  float4 lg = *(const float4*)(logits + (size_t)t * 4);
  float mm = ((masks[b * N + i] > 0) && (masks[b * N + j] > 0)) ? 1.0f : 0.0f;
  size_t base = (size_t)b * RNUM * N * N + rem;
  P[base + 0 * (size_t)N * N] = (_Float16)(mm * sigmoidf_(lg.x));
  P[base + 1 * (size_t)N * N] = (_Float16)(mm * sigmoidf_(lg.y));
  P[base + 2 * (size_t)N * N] = (_Float16)(mm * sigmoidf_(lg.z));
  P[base + 3 * (size_t)N * N] = (_Float16)(mm * sigmoidf_(lg.w));
}

// Work kernel (f16 path), two roles by blockIdx.x:
//  bid <  NCOLB : colsum role — Sum_c csum_c*(N-csum_c)  (factorized Sum(x);
//                 lanes read consecutive c at fixed a -> coalesced)
//  bid >= NCOLB : main role — Sum |rab - a_c*b_c| via packed f16:
//    per 2 elements: v_pk_fma_f16 + v_and (packed abs) + v_dot2_f32_f16
//    = 1.5 VALU inst/elem, f32 accumulation via dot2.
// LDS tiles [c][x] f16, stride LSTR=136 (272 B): conflict-free (verified).
// Occupancy notes (R8): CSPLIT=16 -> 2064 blocks (~8/CU); LDS 8x17.9=143 KB
// and VGPR 32 (<=64) both allow 8 blocks/CU. No min-waves clamp — R6's
// (256,2) + 4-blocks/CU grid left occupancy at 27%, VALUBusy 64%.
// NOTE: broadcast uses scalar extract {as,as} — __builtin_shufflevector
// requires syntactically-constant indices (R7 compile fail).
__global__ __launch_bounds__(256) void work_f16_kernel(const _Float16* __restrict__ P,
                                                       float* __restrict__ out) {
  __shared__ _Float16 tA[CT][LSTR];
  __shared__ _Float16 tB[CT][LSTR];
  __shared__ float wsum[4];

  const int tid = threadIdx.x;
  const int bid = blockIdx.x;

  if (bid < NCOLB) {
    // ---- colsum role ----
    const int s    = bid >> 1;
    const int half = bid & 1;
    const int c    = half * 256 + tid;
    const _Float16* col = P + (size_t)s * N * N + c;
    float sum = 0.0f;
#pragma unroll 8
    for (int a = 0; a < N; ++a) sum += (float)col[(size_t)a * N];
    float v = sum * ((float)N - sum);
    for (int off = 32; off > 0; off >>= 1) v += __shfl_down(v, off, 64);
    const int wid = tid >> 6;
    if ((tid & 63) == 0) wsum[wid] = v;
    __syncthreads();
    if (tid == 0)
      atomicAdd(out, (wsum[0] + wsum[1] + wsum[2] + wsum[3]) * SCALE);
    return;
  }

  // ---- main role ----
  const int m  = bid - NCOLB;
  const int bt = m & 3;
  const int at = (m >> 2) & 3;
  const int s  = (m >> 4) & 7;
  const int cz = m >> 7;                    // 0..CSPLIT-1
  const int a0 = at * TILE;
  const int b0 = bt * TILE;
  const int c0 = cz * CT;                   // exactly one CT-chunk per block

  const int ta = tid & 15;    // a cols (tile-local): ta*4+0..3 and 64+ta*4+0..3
  const int tb = tid >> 4;    // b cols (tile-local): tb*4+0..3 and 64+tb*4+0..3

  const _Float16* Ph = P + (size_t)s * N * N;

  // rab as f16 pairs over y: rab2[x][yp] = {rab[x][2yp], rab[x][2yp+1]}
  half2_t rab2[8][4];
#pragma unroll
  for (int x = 0; x < 8; ++x) {
    int ga = a0 + ((x >> 2) << 6) + ta * 4 + (x & 3);
    uint2 u0 = *(const uint2*)(Ph + (size_t)ga * N + b0 + tb * 4);
    uint2 u1 = *(const uint2*)(Ph + (size_t)ga * N + b0 + 64 + tb * 4);
    rab2[x][0] = u2h(u0.x); rab2[x][1] = u2h(u0.y);
    rab2[x][2] = u2h(u1.x); rab2[x][3] = u2h(u1.y);
  }

  float acc[8];
#pragma unroll
  for (int x = 0; x < 8; ++x) acc[x] = 0.0f;

  const half2_t kOne = {(_Float16)1.0f, (_Float16)1.0f};

  // staging: this thread transposes one tile row (64 B of c) into LDS col sx
  {
    const int sx   = tid & 127;
    const int sarr = tid >> 7;                // 0 -> A, 1 -> B
    const _Float16* srow = Ph + (size_t)((sarr ? b0 : a0) + sx) * N;
    _Float16* dcol = sarr ? &tB[0][sx] : &tA[0][sx];
    const uint4* src = (const uint4*)(srow + c0);
    uint4 q0 = src[0];
    uint4 q1 = src[1];
    uint4 q2 = src[2];
    uint4 q3 = src[3];
    unsigned int w[16] = {q0.x, q0.y, q0.z, q0.w, q1.x, q1.y, q1.z, q1.w,
                          q2.x, q2.y, q2.z, q2.w, q3.x, q3.y, q3.z, q3.w};
    union { unsigned int u32; _Float16 h[2]; } cv;
#pragma unroll
    for (int k = 0; k < 16; ++k) {
      cv.u32 = w[k];
      dcol[(size_t)(2 * k) * LSTR]     = cv.h[0];
      dcol[(size_t)(2 * k + 1) * LSTR] = cv.h[1];
    }
  }
  __syncthreads();

#pragma unroll 4
  for (int c = 0; c < CT; ++c) {
    uint2 ua0 = *(const uint2*)&tA[c][ta * 4];
    uint2 ua1 = *(const uint2*)&tA[c][64 + ta * 4];
    uint2 ub0 = *(const uint2*)&tB[c][tb * 4];
    uint2 ub1 = *(const uint2*)&tB[c][64 + tb * 4];
    half2_t av[4] = {u2h(ua0.x), u2h(ua0.y), u2h(ua1.x), u2h(ua1.y)};
    half2_t bv[4] = {u2h(ub0.x), u2h(ub0.y), u2h(ub1.x), u2h(ub1.y)};
#pragma unroll
    for (int x = 0; x < 8; ++x) {
      _Float16 as = (x & 1) ? av[x >> 1].y : av[x >> 1].x;
      half2_t asp = {as, as};
      float a_ = acc[x];
#pragma unroll
      for (int yp = 0; yp < 4; ++yp) {
        half2_t t2 = rab2[x][yp] - asp * bv[yp];     // v_pk_fma_f16 (neg)
        half2_t p2 = u2h(h2u(t2) & 0x7FFF7FFFu);     // packed |t|
        a_ = fdot2_(p2, kOne, a_);                   // f32 accumulate
      }
      acc[x] = a_;
    }
  }

  float tsum = 0.0f;
#pragma unroll
  for (int x = 0; x < 8; ++x) tsum += acc[x];

  for (int off = 32; off > 0; off >>= 1) tsum += __shfl_down(tsum, off, 64);

  const int wid = tid >> 6;
  if ((tid & 63) == 0) wsum[wid] = tsum;
  __syncthreads();
  if (tid == 0)
    atomicAdd(out, (wsum[0] + wsum[1] + wsum[2] + wsum[3]) * SCALE);
}

// ---------------- f32 fallback (no workspace): R4 structure ----------------
#define FCT    64
#define FSTR   132
#define FCSPL  4

__global__ __launch_bounds__(256, 2) void work_f32_fallback(const float* __restrict__ logits,
                                                            const int* __restrict__ masks,
                                                            float* __restrict__ out) {
  __shared__ __align__(16) float tA[FCT][FSTR];
  __shared__ __align__(16) float tB[FCT][FSTR];
  __shared__ float wsum[4];

  const int tid = threadIdx.x;
  const int bid = blockIdx.x;

  if (bid < NCOLB) {
    const int s    = bid >> 1;
    const int half = bid & 1;
    const int c    = half * 256 + tid;
    const int bb   = s >> 2;
    const int r    = s & 3;
    const int* mrow = masks + bb * N;
    float mc = (mrow[c] > 0) ? 1.0f : 0.0f;
    float sum = 0.0f;
#pragma unroll 4
    for (int a = 0; a < N; ++a) {
      float ma = (mrow[a] > 0) ? 1.0f : 0.0f;
      size_t idx = ((size_t)(bb * N + a) * N + c) * RNUM + r;
      sum += sigmoidf_(logits[idx]) * ma * mc;
    }
    float v = sum * ((float)N - sum);
    for (int off = 32; off > 0; off >>= 1) v += __shfl_down(v, off, 64);
    const int wid = tid >> 6;
    if ((tid & 63) == 0) wsum[wid] = v;
    __syncthreads();
    if (tid == 0)
      atomicAdd(out, (wsum[0] + wsum[1] + wsum[2] + wsum[3]) * SCALE);
    return;
  }

  const int m  = bid - NCOLB;
  const int bt = m & 3;
  const int at = (m >> 2) & 3;
  const int s  = (m >> 4) & 7;
  const int cz = m >> 7;
  const int a0 = at * TILE;
  const int b0 = bt * TILE;
  const int bb = s >> 2;
  const int r  = s & 3;
  const int cbeg = cz * (N / FCSPL);
  const int cend = cbeg + (N / FCSPL);

  const int ta = tid & 15;
  const int tb = tid >> 4;
  const int* mrow = masks + bb * N;

  float rab[8][8];
#pragma unroll
  for (int x = 0; x < 8; ++x) {
    int ra = a0 + ((x >> 2) << 6) + ta * 4 + (x & 3);
    float ma = (mrow[ra] > 0) ? 1.0f : 0.0f;
#pragma unroll
    for (int y = 0; y < 8; ++y) {
      int cb = b0 + ((y >> 2) << 6) + tb * 4 + (y & 3);
      float mb = (mrow[cb] > 0) ? 1.0f : 0.0f;
      size_t idx = ((size_t)(bb * N + ra) * N + cb) * RNUM + r;
      rab[x][y] = sigmoidf_(logits[idx]) * ma * mb;
    }
  }

  float acc[8][2];
#pragma unroll
  for (int x = 0; x < 8; ++x) { acc[x][0] = 0.0f; acc[x][1] = 0.0f; }

  for (int c0 = cbeg; c0 < cend; c0 += FCT) {
    __syncthreads();
#pragma unroll
    for (int it = 0; it < 32; ++it) {
      int e = it * 256 + tid;
      int c = e & 63;
      int i = e >> 6;
      int pc = ((((i >> 2) ^ ((c >> 2) & 31)) & 31) << 2) | (i & 3);
      float mc = (mrow[c0 + c] > 0) ? 1.0f : 0.0f;
      {
        float mi = (mrow[a0 + i] > 0) ? 1.0f : 0.0f;
        size_t idx = ((size_t)(bb * N + a0 + i) * N + (c0 + c)) * RNUM + r;
        tA[c][pc] = sigmoidf_(logits[idx]) * mi * mc;
      }
      {
        float mi = (mrow[b0 + i] > 0) ? 1.0f : 0.0f;
        size_t idx = ((size_t)(bb * N + b0 + i) * N + (c0 + c)) * RNUM + r;
        tB[c][pc] = sigmoidf_(logits[idx]) * mi * mc;
      }
    }
    __syncthreads();

#pragma unroll 2
    for (int cg = 0; cg < FCT / 4; ++cg) {
      const float* pa = &tA[cg * 4][((ta ^ cg) & 31) << 2];
      const float* pb = &tB[cg * 4][((tb ^ cg) & 31) << 2];
#pragma unroll
      for (int dc = 0; dc < 4; ++dc) {
        float4 a0v = *(const float4*)(pa + dc * FSTR);
        float4 a1v = *(const float4*)(pa + dc * FSTR + 64);
        float4 b0v = *(const float4*)(pb + dc * FSTR);
        float4 b1v = *(const float4*)(pb + dc * FSTR + 64);
        float avv[8] = {a0v.x, a0v.y, a0v.z, a0v.w, a1v.x, a1v.y, a1v.z, a1v.w};
        float bvv[8] = {b0v.x, b0v.y, b0v.z, b0v.w, b1v.x, b1v.y, b1v.z, b1v.w};
#pragma unroll
        for (int x = 0; x < 8; ++x) {
#pragma unroll
          for (int y = 0; y < 4; ++y)
            acc[x][0] += fabsf(fmaf(-avv[x], bvv[y], rab[x][y]));
#pragma unroll
          for (int y = 4; y < 8; ++y)
            acc[x][1] += fabsf(fmaf(-avv[x], bvv[y], rab[x][y]));
        }
      }
    }
  }

  float tsum = 0.0f;
#pragma unroll
  for (int x = 0; x < 8; ++x) tsum += acc[x][0] + acc[x][1];
  for (int off = 32; off > 0; off >>= 1) tsum += __shfl_down(tsum, off, 64);
  const int wid = tid >> 6;
  if ((tid & 63) == 0) wsum[wid] = tsum;
  __syncthreads();
  if (tid == 0)
    atomicAdd(out, (wsum[0] + wsum[1] + wsum[2] + wsum[3]) * SCALE);
}

extern "C" void kernel_launch(void* const* d_in, const int* in_sizes, int n_in,
                              void* d_out, int out_size, void* d_ws, size_t ws_size,
                              hipStream_t stream) {
  const float* logits = (const float*)d_in[0];
  const int*   masks  = (const int*)d_in[1];
  float*       out    = (float*)d_out;

  const size_t P_BYTES = (size_t)NSLICE * N * N * sizeof(_Float16);  // 4 MB

  if (ws_size >= P_BYTES) {
    _Float16* P = (_Float16*)d_ws;
    prep_f16_kernel<<<(BNUM * N * N) / 256, 256, 0, stream>>>(logits, masks, P, out);
    const int nblocks = NCOLB + 4 * 4 * NSLICE * CSPLIT;  // 16 + 2048
    work_f16_kernel<<<nblocks, 256, 0, stream>>>(P, out);
  } else {
    zero_out_kernel<<<1, 1, 0, stream>>>(out);
    const int nblocks = NCOLB + 4 * 4 * NSLICE * FCSPL;   // 16 + 512
    work_f32_fallback<<<nblocks, 256, 0, stream>>>(logits, masks, out);
  }
}